// Round 4
// baseline (1000.579 us; speedup 1.0000x reference)
//
#include <hip/hip_runtime.h>

#define BB 64
#define SS 2048
#define HH 128

// LDS-only barrier: drains DS ops (lgkmcnt) but NOT outstanding global
// loads/stores -- keeps per-step prefetch/stores off the critical path.
__device__ __forceinline__ void lds_barrier() {
  asm volatile("s_waitcnt lgkmcnt(0)\n\ts_barrier" ::: "memory");
}

// ---------------------------------------------------------------------------
// GEMM: out[row][j] = in[row][:] @ W[:][j] + bias[j], K=N=128. (proven)
// ---------------------------------------------------------------------------
__global__ __launch_bounds__(256) void gemm128v2(const float* __restrict__ in,
                                                 const float* __restrict__ W,
                                                 const float* __restrict__ bias,
                                                 float* __restrict__ out) {
  __shared__ __align__(16) float xls[128 * 128];   // 64 KB
  __shared__ __align__(16) float wls[128 * 140];   // 70 KB (padded rows)
  const int t = threadIdx.x;
  const long row0 = (long)blockIdx.x * 128;

  {
    const float4* g4 = (const float4*)(in + row0 * 128);
    float4* l4 = (float4*)xls;
#pragma unroll
    for (int it = 0; it < 16; ++it) l4[t + 256 * it] = g4[t + 256 * it];
  }
  {
#pragma unroll
    for (int it = 0; it < 16; ++it) {
      const int fidx = (t + 256 * it) * 4;
      const int k = fidx >> 7, j = fidx & 127;
      const float4 v = *(const float4*)(W + fidx);
      *(float4*)(wls + k * 140 + j + 4 * (j >> 5)) = v;
    }
  }
  __syncthreads();

  const int rg = t >> 4, cg = t & 15;
  const float* xrow = xls + (rg * 8) * 128;
  const float* wcol = wls + cg * 8 + 4 * (cg >> 2);

  float4 acc0[8], acc1[8];
#pragma unroll
  for (int r = 0; r < 8; ++r) {
    acc0[r] = make_float4(0.f, 0.f, 0.f, 0.f);
    acc1[r] = make_float4(0.f, 0.f, 0.f, 0.f);
  }

  for (int k = 0; k < 128; k += 4) {
    float4 xv[8];
#pragma unroll
    for (int r = 0; r < 8; ++r) xv[r] = *(const float4*)(xrow + r * 128 + k);
#pragma unroll
    for (int kk = 0; kk < 4; ++kk) {
      const float* wr = wcol + (k + kk) * 140;
      const float4 w0 = *(const float4*)(wr);
      const float4 w1 = *(const float4*)(wr + 4);
#pragma unroll
      for (int r = 0; r < 8; ++r) {
        const float xs = (kk == 0) ? xv[r].x : (kk == 1) ? xv[r].y
                       : (kk == 2) ? xv[r].z : xv[r].w;
        acc0[r].x = fmaf(xs, w0.x, acc0[r].x);
        acc0[r].y = fmaf(xs, w0.y, acc0[r].y);
        acc0[r].z = fmaf(xs, w0.z, acc0[r].z);
        acc0[r].w = fmaf(xs, w0.w, acc0[r].w);
        acc1[r].x = fmaf(xs, w1.x, acc1[r].x);
        acc1[r].y = fmaf(xs, w1.y, acc1[r].y);
        acc1[r].z = fmaf(xs, w1.z, acc1[r].z);
        acc1[r].w = fmaf(xs, w1.w, acc1[r].w);
      }
    }
  }

  const float4 b0 = *(const float4*)(bias + cg * 8);
  const float4 b1 = *(const float4*)(bias + cg * 8 + 4);
  float* op = out + (row0 + rg * 8) * 128 + cg * 8;
#pragma unroll
  for (int r = 0; r < 8; ++r) {
    float4 o0, o1;
    o0.x = acc0[r].x + b0.x; o0.y = acc0[r].y + b0.y;
    o0.z = acc0[r].z + b0.z; o0.w = acc0[r].w + b0.w;
    o1.x = acc1[r].x + b1.x; o1.y = acc1[r].y + b1.y;
    o1.z = acc1[r].z + b1.z; o1.w = acc1[r].w + b1.w;
    *(float4*)(op + r * 128) = o0;
    *(float4*)(op + r * 128 + 4) = o1;
  }
}

// ---------------------------------------------------------------------------
// Recurrence: h_t = relu(tanh(xi_t + h_{t-1} @ Wh)).
// R3 post-mortem: named float4s + __launch_bounds__(256,1) STILL gave
// VGPR=56 (< the 64 weight floats) -> weights were re-materialized every
// step (~250-330cyc of the 881cyc/step). launch_bounds' 2nd arg is only a
// MIN-waves hint; the backend still register-minimized for an occupancy
// this kernel can never have (64 WGs on 256 CUs = 1 wave/SIMD always).
// Fix: amdgpu_waves_per_eu(1,1) -- capping MAX waves/EU at 1 makes
// spilling worthless to the allocator, so the 64 weight VGPRs stay live.
// VERIFICATION BIT: VGPR_Count must jump to ~100-130. If it stays ~56,
// the backend refuses per-lane weight residency entirely -> pivot.
// Everything else identical to R3 (decomposition jg=tid>>3 x kg=tid&7,
// permuted-component static reduce tree, chunked h layout stride-20,
// lgkm-only barrier, PF=8 xi prefetch).
// ---------------------------------------------------------------------------
#define F4(s, W, A)                                                   \
  A.x = fmaf(s, W.x, A.x); A.y = fmaf(s, W.y, A.y);                   \
  A.z = fmaf(s, W.z, A.z); A.w = fmaf(s, W.w, A.w);

__global__ __attribute__((amdgpu_waves_per_eu(1, 1)))
__launch_bounds__(256) void rnn_rec4w(float* __restrict__ xi,
                                      const float* __restrict__ Wh) {
  __shared__ __align__(16) float hbuf[2][160];  // 8 chunks x (16+4 pad)
  const int tid = threadIdx.x;
  const int jg = tid >> 3;  // col-group: cols jg*4 .. jg*4+3
  const int kg = tid & 7;   // k-slice:  k    kg*16 .. kg*16+15

  // per-lane component permutation for the static reduce tree
  const int c0 = kg & 3, c1 = c0 ^ 1, c2 = c0 ^ 2, c3 = c0 ^ 3;
  const float* wbase = Wh + (kg * 16) * HH + jg * 4;
#define LDW(q) make_float4(wbase[(q) * HH + c0], wbase[(q) * HH + c1], \
                           wbase[(q) * HH + c2], wbase[(q) * HH + c3])
  const float4 W0 = LDW(0),  W1 = LDW(1),  W2 = LDW(2),  W3 = LDW(3);
  const float4 W4 = LDW(4),  W5 = LDW(5),  W6 = LDW(6),  W7 = LDW(7);
  const float4 W8 = LDW(8),  W9 = LDW(9),  W10 = LDW(10), W11 = LDW(11);
  const float4 W12 = LDW(12), W13 = LDW(13), W14 = LDW(14), W15 = LDW(15);
#undef LDW

  if (tid < 160) hbuf[0][tid] = 0.0f;  // h_{-1} = 0 (incl. pads)

  const int col = jg * 4 + c0;                     // owned col (kg<4 lanes)
  const int hwoff = (col >> 4) * 20 + (col & 15);  // chunked write slot
  float* xb = xi + (size_t)blockIdx.x * SS * HH + col;

  // xi prefetch: 1 float/lane (owned col), PF steps deep
  constexpr int PF = 8;
  float pre[PF];
  if (kg < 4) {
#pragma unroll
    for (int p = 0; p < PF; ++p) pre[p] = xb[(size_t)p * HH];
  }
  __syncthreads();

  const float* hrd0 = hbuf[0] + kg * 20;
  const float* hrd1 = hbuf[1] + kg * 20;

  for (int t0 = 0; t0 < SS; t0 += PF) {
#pragma unroll
    for (int p = 0; p < PF; ++p) {
      const int t = t0 + p;
      const float4* h4 = (const float4*)((p & 1) ? hrd1 : hrd0);
      const float4 hv0 = h4[0], hv1 = h4[1], hv2 = h4[2], hv3 = h4[3];

      float4 a0 = make_float4(0.f, 0.f, 0.f, 0.f);
      float4 a1 = make_float4(0.f, 0.f, 0.f, 0.f);
      float4 a2 = make_float4(0.f, 0.f, 0.f, 0.f);
      float4 a3 = make_float4(0.f, 0.f, 0.f, 0.f);
      F4(hv0.x, W0, a0)  F4(hv0.y, W1, a1)  F4(hv0.z, W2, a2)  F4(hv0.w, W3, a3)
      F4(hv1.x, W4, a0)  F4(hv1.y, W5, a1)  F4(hv1.z, W6, a2)  F4(hv1.w, W7, a3)
      F4(hv2.x, W8, a0)  F4(hv2.y, W9, a1)  F4(hv2.z, W10, a2) F4(hv2.w, W11, a3)
      F4(hv3.x, W12, a0) F4(hv3.y, W13, a1) F4(hv3.z, W14, a2) F4(hv3.w, W15, a3)

      float4 pp;
      pp.x = (a0.x + a1.x) + (a2.x + a3.x);  // col c0 partial
      pp.y = (a0.y + a1.y) + (a2.y + a3.y);  // col c0^1
      pp.z = (a0.z + a1.z) + (a2.z + a3.z);  // col c0^2
      pp.w = (a0.w + a1.w) + (a2.w + a3.w);  // col c0^3
      // static reduce-scatter over kg (partner's permutation supplies
      // exactly my col): xor1/xor2 are DPP quad_perm, xor4 one ds_swizzle.
      const float q0 = pp.x + __shfl_xor(pp.y, 1);
      const float q1 = pp.z + __shfl_xor(pp.w, 1);
      const float rr = q0 + __shfl_xor(q1, 2);
      const float ss = rr + __shfl_xor(rr, 4);

      if (kg < 4) {
        const float v = ss + pre[p];
        // tanh(v) = 1 - 2/(exp2(2v*log2e)+1); safe at +-inf. relu via fmax.
        const float e = __builtin_amdgcn_exp2f(v * 2.8853900817779268f);
        const float hn =
            fmaxf(1.0f - 2.0f * __builtin_amdgcn_rcpf(e + 1.0f), 0.0f);
        hbuf[(p & 1) ^ 1][hwoff] = hn;   // h for step t+1 (dbuf)
        xb[(size_t)t * HH] = hn;         // hs for the output GEMM
        const int tn = t + PF;
        if (tn < SS) pre[p] = xb[(size_t)tn * HH];
      }
      lds_barrier();
    }
  }
}

extern "C" void kernel_launch(void* const* d_in, const int* in_sizes, int n_in,
                              void* d_out, int out_size, void* d_ws, size_t ws_size,
                              hipStream_t stream) {
  const float* x  = (const float*)d_in[0];
  const float* Wi = (const float*)d_in[1];
  const float* Wh = (const float*)d_in[2];
  const float* b  = (const float*)d_in[3];
  const float* Wo = (const float*)d_in[4];
  const float* bo = (const float*)d_in[5];
  float* y  = (float*)d_out;
  float* xi = (float*)d_ws;  // 64 MB: xi = x@Wi+b, overwritten in-place with hs

  gemm128v2<<<(BB * SS) / 128, 256, 0, stream>>>(x, Wi, b, xi);
  rnn_rec4w<<<BB, 256, 0, stream>>>(xi, Wh);
  gemm128v2<<<(BB * SS) / 128, 256, 0, stream>>>(xi, Wo, bo, y);
}

// Round 6
// 857.712 us; speedup vs baseline: 1.1666x; 1.1666x over previous
//
#include <hip/hip_runtime.h>

#define BB 64
#define SS 2048
#define HH 128

// LDS-only barrier: drains DS ops (lgkmcnt) but NOT outstanding global
// loads/stores -- keeps per-step prefetch/stores off the critical path.
__device__ __forceinline__ void lds_barrier() {
  asm volatile("s_waitcnt lgkmcnt(0)\n\ts_barrier" ::: "memory");
}

// quad_perm DPP: guaranteed v_mov_b32_dpp (VALU, ~4cyc), NOT ds_bpermute.
// ctrl 0xB1 = [1,0,3,2] = xor1; 0x4E = [2,3,0,1] = xor2.
#define QPERM_F(x, ctrl)                                                  \
  __int_as_float(__builtin_amdgcn_update_dpp(0, __float_as_int(x), ctrl,  \
                                             0xF, 0xF, false))

// ---------------------------------------------------------------------------
// GEMM: out[row][j] = in[row][:] @ W[:][j] + bias[j], K=N=128. (proven)
// ---------------------------------------------------------------------------
__global__ __launch_bounds__(256) void gemm128v2(const float* __restrict__ in,
                                                 const float* __restrict__ W,
                                                 const float* __restrict__ bias,
                                                 float* __restrict__ out) {
  __shared__ __align__(16) float xls[128 * 128];   // 64 KB
  __shared__ __align__(16) float wls[128 * 140];   // 70 KB (padded rows)
  const int t = threadIdx.x;
  const long row0 = (long)blockIdx.x * 128;

  {
    const float4* g4 = (const float4*)(in + row0 * 128);
    float4* l4 = (float4*)xls;
#pragma unroll
    for (int it = 0; it < 16; ++it) l4[t + 256 * it] = g4[t + 256 * it];
  }
  {
#pragma unroll
    for (int it = 0; it < 16; ++it) {
      const int fidx = (t + 256 * it) * 4;
      const int k = fidx >> 7, j = fidx & 127;
      const float4 v = *(const float4*)(W + fidx);
      *(float4*)(wls + k * 140 + j + 4 * (j >> 5)) = v;
    }
  }
  __syncthreads();

  const int rg = t >> 4, cg = t & 15;
  const float* xrow = xls + (rg * 8) * 128;
  const float* wcol = wls + cg * 8 + 4 * (cg >> 2);

  float4 acc0[8], acc1[8];
#pragma unroll
  for (int r = 0; r < 8; ++r) {
    acc0[r] = make_float4(0.f, 0.f, 0.f, 0.f);
    acc1[r] = make_float4(0.f, 0.f, 0.f, 0.f);
  }

  for (int k = 0; k < 128; k += 4) {
    float4 xv[8];
#pragma unroll
    for (int r = 0; r < 8; ++r) xv[r] = *(const float4*)(xrow + r * 128 + k);
#pragma unroll
    for (int kk = 0; kk < 4; ++kk) {
      const float* wr = wcol + (k + kk) * 140;
      const float4 w0 = *(const float4*)(wr);
      const float4 w1 = *(const float4*)(wr + 4);
#pragma unroll
      for (int r = 0; r < 8; ++r) {
        const float xs = (kk == 0) ? xv[r].x : (kk == 1) ? xv[r].y
                       : (kk == 2) ? xv[r].z : xv[r].w;
        acc0[r].x = fmaf(xs, w0.x, acc0[r].x);
        acc0[r].y = fmaf(xs, w0.y, acc0[r].y);
        acc0[r].z = fmaf(xs, w0.z, acc0[r].z);
        acc0[r].w = fmaf(xs, w0.w, acc0[r].w);
        acc1[r].x = fmaf(xs, w1.x, acc1[r].x);
        acc1[r].y = fmaf(xs, w1.y, acc1[r].y);
        acc1[r].z = fmaf(xs, w1.z, acc1[r].z);
        acc1[r].w = fmaf(xs, w1.w, acc1[r].w);
      }
    }
  }

  const float4 b0 = *(const float4*)(bias + cg * 8);
  const float4 b1 = *(const float4*)(bias + cg * 8 + 4);
  float* op = out + (row0 + rg * 8) * 128 + cg * 8;
#pragma unroll
  for (int r = 0; r < 8; ++r) {
    float4 o0, o1;
    o0.x = acc0[r].x + b0.x; o0.y = acc0[r].y + b0.y;
    o0.z = acc0[r].z + b0.z; o0.w = acc0[r].w + b0.w;
    o1.x = acc1[r].x + b1.x; o1.y = acc1[r].y + b1.y;
    o1.z = acc1[r].z + b1.z; o1.w = acc1[r].w + b1.w;
    *(float4*)(op + r * 128) = o0;
    *(float4*)(op + r * 128 + 4) = o1;
  }
}

// ---------------------------------------------------------------------------
// Recurrence: h_t = relu(tanh(xi_t + h_{t-1} @ Wh)).
// R4 post-mortem: weight residency (VGPR 56->132) changed NOTHING ->
// reloads were hidden. The real cost: HIP __shfl_xor lowers to
// ds_bpermute_b32 (LDS pipe, ~120cyc latency). R3 had THREE in a serial
// chain (xor1,xor2,xor4) = ~350cyc -- model 510 + 350 = 860 ~= measured 880.
// Fix: decomposition needing only xor1+xor2, emitted as explicit quad_perm
// DPP (v_mov_b32_dpp, VALU ~4cyc). ZERO LDS-pipe ops between the last FMA
// and the h-write.
// Decomposition: kg=tid&3 (4 k-slices x 32), jg=tid>>2 (64 groups x 2 cols).
// 64 FMA/lane. Weights comp-permuted (x = own col j2+(kg&1), y = partner)
// so both fold levels are static adds of a quad_perm value. DS reads: 8x
// b128/lane from chunk kg (stride 36 floats: per-instr addresses hit bank
// groups {4kg+4q}, conflict-free). This doubles DS pipe traffic vs R3 --
// overlappable -- to delete ~350cyc of serial shuffle latency.
// (R5 was an infra flake -- container failed before running; resubmitted
// unchanged. Barrier uniformity + DPP reduction algebra re-audited.)
// ---------------------------------------------------------------------------
#define FQ(hv, Wa, Wb, Wc, Wd)                                     \
  a0.x = fmaf(hv.x, Wa.x, a0.x); a0.y = fmaf(hv.x, Wa.y, a0.y);    \
  a1.x = fmaf(hv.y, Wb.x, a1.x); a1.y = fmaf(hv.y, Wb.y, a1.y);    \
  a2.x = fmaf(hv.z, Wc.x, a2.x); a2.y = fmaf(hv.z, Wc.y, a2.y);    \
  a3.x = fmaf(hv.w, Wd.x, a3.x); a3.y = fmaf(hv.w, Wd.y, a3.y);

__global__ __attribute__((amdgpu_waves_per_eu(1, 1)))
__launch_bounds__(256) void rnn_dpp(float* __restrict__ xi,
                                    const float* __restrict__ Wh) {
  __shared__ __align__(16) float hbuf[2][144];  // 4 chunks x (32+4 pad)
  const int tid = threadIdx.x;
  const int jg = tid >> 2;  // col-group: cols jg*2, jg*2+1
  const int kg = tid & 3;   // k-slice:  k in kg*32 .. kg*32+31
  const int j2 = jg * 2;

  // comp-permuted weights: .x = own col, .y = partner col
  const int cown = j2 + (kg & 1);
  const int cpart = j2 + ((kg & 1) ^ 1);
  const float* wbase = Wh + (kg * 32) * HH;
#define LDW2(q) make_float2(wbase[(q) * HH + cown], wbase[(q) * HH + cpart])
  const float2 W00 = LDW2(0),  W01 = LDW2(1),  W02 = LDW2(2),  W03 = LDW2(3);
  const float2 W04 = LDW2(4),  W05 = LDW2(5),  W06 = LDW2(6),  W07 = LDW2(7);
  const float2 W08 = LDW2(8),  W09 = LDW2(9),  W10 = LDW2(10), W11 = LDW2(11);
  const float2 W12 = LDW2(12), W13 = LDW2(13), W14 = LDW2(14), W15 = LDW2(15);
  const float2 W16 = LDW2(16), W17 = LDW2(17), W18 = LDW2(18), W19 = LDW2(19);
  const float2 W20 = LDW2(20), W21 = LDW2(21), W22 = LDW2(22), W23 = LDW2(23);
  const float2 W24 = LDW2(24), W25 = LDW2(25), W26 = LDW2(26), W27 = LDW2(27);
  const float2 W28 = LDW2(28), W29 = LDW2(29), W30 = LDW2(30), W31 = LDW2(31);
#undef LDW2

  if (tid < 144) hbuf[0][tid] = 0.0f;  // h_{-1} = 0 (incl. pads)

  const int hwoff = (cown >> 5) * 36 + (cown & 31);  // owner write slot
  float* xb = xi + (size_t)blockIdx.x * SS * HH + cown;

  // xi prefetch: 1 float/owner-lane (kg<2), PF steps deep
  constexpr int PF = 8;
  float pre[PF];
  if (kg < 2) {
#pragma unroll
    for (int p = 0; p < PF; ++p) pre[p] = xb[(size_t)p * HH];
  }
  __syncthreads();

  const float* hrd0 = hbuf[0] + kg * 36;
  const float* hrd1 = hbuf[1] + kg * 36;

  for (int t0 = 0; t0 < SS; t0 += PF) {
#pragma unroll
    for (int p = 0; p < PF; ++p) {
      const int t = t0 + p;
      const float4* h4 = (const float4*)((p & 1) ? hrd1 : hrd0);
      const float4 hv0 = h4[0], hv1 = h4[1], hv2 = h4[2], hv3 = h4[3];
      const float4 hv4 = h4[4], hv5 = h4[5], hv6 = h4[6], hv7 = h4[7];

      float2 a0 = make_float2(0.f, 0.f), a1 = make_float2(0.f, 0.f);
      float2 a2 = make_float2(0.f, 0.f), a3 = make_float2(0.f, 0.f);
      FQ(hv0, W00, W01, W02, W03)
      FQ(hv1, W04, W05, W06, W07)
      FQ(hv2, W08, W09, W10, W11)
      FQ(hv3, W12, W13, W14, W15)
      FQ(hv4, W16, W17, W18, W19)
      FQ(hv5, W20, W21, W22, W23)
      FQ(hv6, W24, W25, W26, W27)
      FQ(hv7, W28, W29, W30, W31)

      // partials: .x = own col over slice kg, .y = partner col
      const float px = (a0.x + a1.x) + (a2.x + a3.x);
      const float py = (a0.y + a1.y) + (a2.y + a3.y);
      // reduce over kg -- pure DPP (no LDS-pipe ops):
      // xor1: partner lane's .y IS my col on its slice
      const float q0 = px + QPERM_F(py, 0xB1);
      // xor2: same col, other slice pair
      const float s = q0 + QPERM_F(q0, 0x4E);

      if (kg < 2) {
        const float v = s + pre[p];
        // tanh(v) = 1 - 2/(exp2(2v*log2e)+1); safe at +-inf. relu via fmax.
        const float e = __builtin_amdgcn_exp2f(v * 2.8853900817779268f);
        const float hn =
            fmaxf(1.0f - 2.0f * __builtin_amdgcn_rcpf(e + 1.0f), 0.0f);
        hbuf[(p & 1) ^ 1][hwoff] = hn;   // h for step t+1 (dbuf)
        xb[(size_t)t * HH] = hn;         // hs for the output GEMM
        const int tn = t + PF;
        if (tn < SS) pre[p] = xb[(size_t)tn * HH];
      }
      lds_barrier();
    }
  }
}

extern "C" void kernel_launch(void* const* d_in, const int* in_sizes, int n_in,
                              void* d_out, int out_size, void* d_ws, size_t ws_size,
                              hipStream_t stream) {
  const float* x  = (const float*)d_in[0];
  const float* Wi = (const float*)d_in[1];
  const float* Wh = (const float*)d_in[2];
  const float* b  = (const float*)d_in[3];
  const float* Wo = (const float*)d_in[4];
  const float* bo = (const float*)d_in[5];
  float* y  = (float*)d_out;
  float* xi = (float*)d_ws;  // 64 MB: xi = x@Wi+b, overwritten in-place with hs

  gemm128v2<<<(BB * SS) / 128, 256, 0, stream>>>(x, Wi, b, xi);
  rnn_dpp<<<BB, 256, 0, stream>>>(xi, Wh);
  gemm128v2<<<(BB * SS) / 128, 256, 0, stream>>>(xi, Wo, bo, y);
}

// Round 8
// 850.006 us; speedup vs baseline: 1.1771x; 1.0091x over previous
//
#include <hip/hip_runtime.h>

#define BB 64
#define SS 2048
#define HH 128

// LDS-only barrier: drains DS ops (lgkmcnt) but NOT outstanding global
// loads/stores -- keeps per-step prefetch/stores off the critical path.
__device__ __forceinline__ void lds_barrier() {
  asm volatile("s_waitcnt lgkmcnt(0)\n\ts_barrier" ::: "memory");
}

// quad_perm DPP: guaranteed v_mov_b32_dpp (VALU, ~4cyc), NOT ds_bpermute.
// ctrl 0xB1 = [1,0,3,2] = xor1; 0x4E = [2,3,0,1] = xor2.
#define QPERM_F(x, ctrl)                                                  \
  __int_as_float(__builtin_amdgcn_update_dpp(0, __float_as_int(x), ctrl,  \
                                             0xF, 0xF, false))

// ---------------------------------------------------------------------------
// GEMM: out[row][j] = in[row][:] @ W[:][j] + bias[j], K=N=128. (proven)
// ---------------------------------------------------------------------------
__global__ __launch_bounds__(256) void gemm128v2(const float* __restrict__ in,
                                                 const float* __restrict__ W,
                                                 const float* __restrict__ bias,
                                                 float* __restrict__ out) {
  __shared__ __align__(16) float xls[128 * 128];   // 64 KB
  __shared__ __align__(16) float wls[128 * 140];   // 70 KB (padded rows)
  const int t = threadIdx.x;
  const long row0 = (long)blockIdx.x * 128;

  {
    const float4* g4 = (const float4*)(in + row0 * 128);
    float4* l4 = (float4*)xls;
#pragma unroll
    for (int it = 0; it < 16; ++it) l4[t + 256 * it] = g4[t + 256 * it];
  }
  {
#pragma unroll
    for (int it = 0; it < 16; ++it) {
      const int fidx = (t + 256 * it) * 4;
      const int k = fidx >> 7, j = fidx & 127;
      const float4 v = *(const float4*)(W + fidx);
      *(float4*)(wls + k * 140 + j + 4 * (j >> 5)) = v;
    }
  }
  __syncthreads();

  const int rg = t >> 4, cg = t & 15;
  const float* xrow = xls + (rg * 8) * 128;
  const float* wcol = wls + cg * 8 + 4 * (cg >> 2);

  float4 acc0[8], acc1[8];
#pragma unroll
  for (int r = 0; r < 8; ++r) {
    acc0[r] = make_float4(0.f, 0.f, 0.f, 0.f);
    acc1[r] = make_float4(0.f, 0.f, 0.f, 0.f);
  }

  for (int k = 0; k < 128; k += 4) {
    float4 xv[8];
#pragma unroll
    for (int r = 0; r < 8; ++r) xv[r] = *(const float4*)(xrow + r * 128 + k);
#pragma unroll
    for (int kk = 0; kk < 4; ++kk) {
      const float* wr = wcol + (k + kk) * 140;
      const float4 w0 = *(const float4*)(wr);
      const float4 w1 = *(const float4*)(wr + 4);
#pragma unroll
      for (int r = 0; r < 8; ++r) {
        const float xs = (kk == 0) ? xv[r].x : (kk == 1) ? xv[r].y
                       : (kk == 2) ? xv[r].z : xv[r].w;
        acc0[r].x = fmaf(xs, w0.x, acc0[r].x);
        acc0[r].y = fmaf(xs, w0.y, acc0[r].y);
        acc0[r].z = fmaf(xs, w0.z, acc0[r].z);
        acc0[r].w = fmaf(xs, w0.w, acc0[r].w);
        acc1[r].x = fmaf(xs, w1.x, acc1[r].x);
        acc1[r].y = fmaf(xs, w1.y, acc1[r].y);
        acc1[r].z = fmaf(xs, w1.z, acc1[r].z);
        acc1[r].w = fmaf(xs, w1.w, acc1[r].w);
      }
    }
  }

  const float4 b0 = *(const float4*)(bias + cg * 8);
  const float4 b1 = *(const float4*)(bias + cg * 8 + 4);
  float* op = out + (row0 + rg * 8) * 128 + cg * 8;
#pragma unroll
  for (int r = 0; r < 8; ++r) {
    float4 o0, o1;
    o0.x = acc0[r].x + b0.x; o0.y = acc0[r].y + b0.y;
    o0.z = acc0[r].z + b0.z; o0.w = acc0[r].w + b0.w;
    o1.x = acc1[r].x + b1.x; o1.y = acc1[r].y + b1.y;
    o1.z = acc1[r].z + b1.z; o1.w = acc1[r].w + b1.w;
    *(float4*)(op + r * 128) = o0;
    *(float4*)(op + r * 128 + 4) = o1;
  }
}

// ---------------------------------------------------------------------------
// Recurrence: h_t = relu(tanh(xi_t + h_{t-1} @ Wh)).
// R7 post-mortem (absmax 0.89): the hand-asm mov+permlane_swap block had
// (1) NO software wait states -- CDNA requires ~2 between a VALU VGPR
//     write and a DPP/permlane-class op READING it; compiler inserts them
//     for builtin DPP, but inside one asm block that's on us. The swap read
//     %1 zero instrs after the mov wrote it -> stale register -> garbage.
// (2) a direction assumption (dst-odd<->src-even rows) in the va/vb select.
// Fixes: s_nop 1 between mov and swap; direction-agnostic folds:
//     after mov+swap, {va,vb} = {r1[lane], r1[lane^16]} in SOME order, so
//     partner = (va+vb) - r1 (exact to ~1ulp), and the final xor32 fold is
//     own+partner so sfin = wa + wbv directly (bit-exact, no select).
// Structure unchanged from R7: 16-way k-split, 8 h-floats/lane (2x b128 =
// 8 wave-instrs/CU/step vs R6's 32 -- DS register-delivery was the floor),
// reduce = xor1+xor2 quad_perm DPP + xor16/xor32 permlane swaps, all VALU.
// ---------------------------------------------------------------------------
#define FK(hk, WA, WB)                                                 \
  pA.x = fmaf(hk, WA.x, pA.x); pA.y = fmaf(hk, WA.y, pA.y);            \
  pA.z = fmaf(hk, WA.z, pA.z); pA.w = fmaf(hk, WA.w, pA.w);            \
  pB.x = fmaf(hk, WB.x, pB.x); pB.y = fmaf(hk, WB.y, pB.y);            \
  pB.z = fmaf(hk, WB.z, pB.z); pB.w = fmaf(hk, WB.w, pB.w);

__global__ __attribute__((amdgpu_waves_per_eu(1, 1)))
__launch_bounds__(256) void rnn_dpp16(float* __restrict__ xi,
                                      const float* __restrict__ Wh) {
  __shared__ __align__(16) float hbuf[2][192];  // 16 chunks x (8+4 pad)
  const int tid = threadIdx.x;
  const int l = tid & 63;
  const int w = tid >> 6;
  const int f = (l & 3) | (((l >> 4) & 1) << 2);   // fold bits 0,1,4
  const int K = f | (((l >> 5) & 1) << 3);         // k-slice 0..15
  const int jg = ((l >> 2) & 3) | (w << 2);        // col-group 0..15
  const bool own = ((l >> 5) & 1) == 0;            // 128 owners, 1 col each
  const int col = jg * 8 + f;

  // weights: slot s of W{k}A/B = Wh[K*8+k][jg*8 + (s^f)]  (16 named float4)
  const float* wb_ = Wh + (K * 8) * HH + jg * 8;
#define LW(k)                                                              \
  const float4 W##k##A = make_float4(wb_[(k) * HH + (0 ^ f)],              \
                                     wb_[(k) * HH + (1 ^ f)],              \
                                     wb_[(k) * HH + (2 ^ f)],              \
                                     wb_[(k) * HH + (3 ^ f)]);             \
  const float4 W##k##B = make_float4(wb_[(k) * HH + (4 ^ f)],              \
                                     wb_[(k) * HH + (5 ^ f)],              \
                                     wb_[(k) * HH + (6 ^ f)],              \
                                     wb_[(k) * HH + (7 ^ f)]);
  LW(0) LW(1) LW(2) LW(3) LW(4) LW(5) LW(6) LW(7)
#undef LW

  if (tid < 192) hbuf[0][tid] = 0.0f;  // h_{-1} = 0 (incl. pads)

  const int rdoff = K * 12;                        // my k-slice chunk
  const int wroff = (col >> 3) * 12 + (col & 7);   // owner write slot
  float* xb = xi + (size_t)blockIdx.x * SS * HH + col;

  // xi prefetch: owners only, PF steps deep
  constexpr int PF = 8;
  float pre[PF];
#pragma unroll
  for (int p = 0; p < PF; ++p) pre[p] = 0.0f;
  if (own) {
#pragma unroll
    for (int p = 0; p < PF; ++p) pre[p] = xb[(size_t)p * HH];
  }
  __syncthreads();

  for (int t0 = 0; t0 < SS; t0 += PF) {
#pragma unroll
    for (int p = 0; p < PF; ++p) {
      const int t = t0 + p;
      const float* hb = hbuf[p & 1] + rdoff;  // t&1==p&1 (PF even)
      const float4 h0 = *(const float4*)(hb);
      const float4 h1 = *(const float4*)(hb + 4);

      float4 pA = make_float4(0.f, 0.f, 0.f, 0.f);
      float4 pB = make_float4(0.f, 0.f, 0.f, 0.f);
      FK(h0.x, W0A, W0B) FK(h0.y, W1A, W1B)
      FK(h0.z, W2A, W2B) FK(h0.w, W3A, W3B)
      FK(h1.x, W4A, W4B) FK(h1.y, W5A, W5B)
      FK(h1.z, W6A, W6B) FK(h1.w, W7A, W7B)

      // reduce over the 16 k-slices -- ALL VALU, zero LDS-pipe ops:
      const float q0 = pA.x + QPERM_F(pA.y, 0xB1);   // xor1
      const float q1 = pA.z + QPERM_F(pA.w, 0xB1);
      const float q2 = pB.x + QPERM_F(pB.y, 0xB1);
      const float q3 = pB.z + QPERM_F(pB.w, 0xB1);
      const float r0 = q0 + QPERM_F(q1, 0x4E);       // xor2
      const float r1 = q2 + QPERM_F(q3, 0x4E);
      // xor16 via v_permlane16_swap: after mov+swap (s_nop 1 covers the
      // VALU->permlane read hazard), {va,vb} = {r1[l], r1[l^16]} in a HW-
      // defined order; partner = (va+vb)-r1 regardless of direction.
      int va = __float_as_int(r1), vb;
      asm volatile("v_mov_b32 %1, %0\n\ts_nop 1\n\tv_permlane16_swap_b32 %0, %1"
                   : "+v"(va), "=&v"(vb));
      const float tt =
          r0 + ((__int_as_float(va) + __int_as_float(vb)) - r1);
      // xor32 via v_permlane32_swap: {wa,wbv} = {tt[l], tt[l^32]} -> the
      // fold is own+partner, so the plain sum IS the result (bit-exact).
      int wa = __float_as_int(tt), wbv;
      asm volatile("v_mov_b32 %1, %0\n\ts_nop 1\n\tv_permlane32_swap_b32 %0, %1"
                   : "+v"(wa), "=&v"(wbv));
      const float sfin = __int_as_float(wa) + __int_as_float(wbv);

      const float v = sfin + pre[p];
      // tanh(v) = 1 - 2/(exp2(2v*log2e)+1); safe at +-inf. relu via fmax.
      const float e = __builtin_amdgcn_exp2f(v * 2.8853900817779268f);
      const float hn =
          fmaxf(1.0f - 2.0f * __builtin_amdgcn_rcpf(e + 1.0f), 0.0f);

      if (own) {
        hbuf[(p & 1) ^ 1][wroff] = hn;   // h for step t+1 (dbuf)
        xb[(size_t)t * HH] = hn;         // hs for the output GEMM
        const int tn = t + PF;
        if (tn < SS) pre[p] = xb[(size_t)tn * HH];
      }
      lds_barrier();
    }
  }
}

extern "C" void kernel_launch(void* const* d_in, const int* in_sizes, int n_in,
                              void* d_out, int out_size, void* d_ws, size_t ws_size,
                              hipStream_t stream) {
  const float* x  = (const float*)d_in[0];
  const float* Wi = (const float*)d_in[1];
  const float* Wh = (const float*)d_in[2];
  const float* b  = (const float*)d_in[3];
  const float* Wo = (const float*)d_in[4];
  const float* bo = (const float*)d_in[5];
  float* y  = (float*)d_out;
  float* xi = (float*)d_ws;  // 64 MB: xi = x@Wi+b, overwritten in-place with hs

  gemm128v2<<<(BB * SS) / 128, 256, 0, stream>>>(x, Wi, b, xi);
  rnn_dpp16<<<BB, 256, 0, stream>>>(xi, Wh);
  gemm128v2<<<(BB * SS) / 128, 256, 0, stream>>>(xi, Wo, bo, y);
}